// Round 9
// baseline (416.764 us; speedup 1.0000x reference)
//
#include <hip/hip_runtime.h>
#include <cstdint>

typedef unsigned short u16;
typedef float f32x4 __attribute__((ext_vector_type(4)));
typedef float f32x16 __attribute__((ext_vector_type(16)));
typedef __bf16 bf16x8 __attribute__((ext_vector_type(8)));

#define LOG2E 1.44269504088896340736f

// ---------- helpers ----------
__device__ __forceinline__ u16 f2bf(float f) {
    union { float f; unsigned u; } v; v.f = f;
    unsigned r = v.u + 0x7fffu + ((v.u >> 16) & 1u);   // RNE
    return (u16)(r >> 16);
}

__device__ __forceinline__ float bf2f(u16 v) {
    union { unsigned u; float f; } x; x.u = ((unsigned)v) << 16; return x.f;
}

__device__ __forceinline__ unsigned cvt_pk_bf16(float lo, float hi) {
    unsigned r;
    asm("v_cvt_pk_bf16_f32 %0, %1, %2" : "=v"(r) : "v"(lo), "v"(hi));
    return r;
}

__device__ __forceinline__ float exp2_hw(float x) {
    float r;
    asm("v_exp_f32 %0, %1" : "=v"(r) : "v"(x));
    return r;
}

__device__ __forceinline__ f32x4 mfma16(bf16x8 a, bf16x8 b, f32x4 c) {
    return __builtin_amdgcn_mfma_f32_16x16x32_bf16(a, b, c, 0, 0, 0);
}

__device__ __forceinline__ f32x16 mfma32(bf16x8 a, bf16x8 b, f32x16 c) {
    return __builtin_amdgcn_mfma_f32_32x32x16_bf16(a, b, c, 0, 0, 0);
}

__device__ __forceinline__ void gload_lds16(const void* g, void* l) {
    __builtin_amdgcn_global_load_lds(
        (__attribute__((address_space(1))) unsigned int*)(g),
        (__attribute__((address_space(3))) unsigned int*)(l),
        16, 0, 0);
}

// ---------- constants ----------
#define MB_TOK 8192      // B*S
#define DM 768
#define HH 12
#define DHD 64
#define NWAY 4
#define DFF 3072
#define SEQ 2048
#define NBATCH 4

// ---------- fused prep: LN + 6 weight transposes + bias concat + routing ----------
#define PREP_LN_END   8192
#define PREP_T7_END   10496
#define PREP_W1_END   19712
#define PREP_W2_END   28928
#define PREP_CB_END   28937
#define PREP_GRID     28938

__global__ __launch_bounds__(256) void prep_kernel(
    const float* __restrict__ x, const float* __restrict__ ln_g,
    const float* __restrict__ ln_b, u16* __restrict__ xn,
    const float* __restrict__ wq, const float* __restrict__ wk,
    const float* __restrict__ wvv, const float* __restrict__ wo,
    u16* __restrict__ wqkvt, u16* __restrict__ wot,
    const float* __restrict__ w1, u16* __restrict__ w1t,
    const float* __restrict__ w2, u16* __restrict__ w2t,
    const float* __restrict__ bq, const float* __restrict__ bk,
    const float* __restrict__ bv, float* __restrict__ bqkv,
    const int* __restrict__ wl, int* __restrict__ perm,
    int* __restrict__ eoff, int4* __restrict__ fmap, int4* __restrict__ fmap64)
{
    __shared__ float tl[32][33];
    __shared__ float red[4];
    __shared__ int cnt[4], cur[4], off[5];
    int bid = blockIdx.x, tid = threadIdx.x;

    if (bid < PREP_LN_END) {                   // ---- LayerNorm row ----
        int row = bid;
        const float* xr = x + (size_t)row * DM;
        float v0 = xr[tid], v1 = xr[tid + 256], v2 = xr[tid + 512];
        float s = v0 + v1 + v2;
        #pragma unroll
        for (int k = 1; k < 64; k <<= 1) s += __shfl_xor(s, k);
        if ((tid & 63) == 0) red[tid >> 6] = s;
        __syncthreads();
        float mu = (red[0] + red[1] + red[2] + red[3]) * (1.f / 768.f);
        float d0 = v0 - mu, d1 = v1 - mu, d2 = v2 - mu;
        float q = d0 * d0 + d1 * d1 + d2 * d2;
        #pragma unroll
        for (int k = 1; k < 64; k <<= 1) q += __shfl_xor(q, k);
        __syncthreads();
        if ((tid & 63) == 0) red[tid >> 6] = q;
        __syncthreads();
        float var = (red[0] + red[1] + red[2] + red[3]) * (1.f / 768.f);
        float rs = rsqrtf(var + 1e-6f);
        u16* xo = xn + (size_t)row * DM;
        xo[tid]       = f2bf(d0 * rs * ln_g[tid]       + ln_b[tid]);
        xo[tid + 256] = f2bf(d1 * rs * ln_g[tid + 256] + ln_b[tid + 256]);
        xo[tid + 512] = f2bf(d2 * rs * ln_g[tid + 512] + ln_b[tid + 512]);
        return;
    }
    if (bid < PREP_W2_END) {                   // ---- weight transposes ----
        const float* src; u16* dst; int K, N, n0, k0;
        if (bid < PREP_T7_END) {
            int r = bid - PREP_LN_END;
            int wsel = r / 576, lb = r % 576;
            K = 768; N = 768;
            n0 = (lb % 24) * 32; k0 = (lb / 24) * 32;
            src = wsel == 0 ? wq : (wsel == 1 ? wk : (wsel == 2 ? wvv : wo));
            dst = wsel == 3 ? wot : (wqkvt + (size_t)wsel * 768 * 768);
        } else if (bid < PREP_W1_END) {
            int lb = bid - PREP_T7_END;
            K = 768; N = 3072;
            n0 = (lb % 96) * 32; k0 = ((lb / 96) % 24) * 32;
            int z = lb / 2304;
            src = w1 + (size_t)z * K * N; dst = w1t + (size_t)z * K * N;
        } else {
            int lb = bid - PREP_W1_END;
            K = 3072; N = 768;
            n0 = (lb % 24) * 32; k0 = ((lb / 24) % 96) * 32;
            int z = lb / 2304;
            src = w2 + (size_t)z * K * N; dst = w2t + (size_t)z * K * N;
        }
        int tx = tid & 31, ty = tid >> 5;
        #pragma unroll
        for (int j = 0; j < 4; ++j)
            tl[ty + j * 8][tx] = src[(size_t)(k0 + ty + j * 8) * N + n0 + tx];
        __syncthreads();
        #pragma unroll
        for (int j = 0; j < 4; ++j)
            dst[(size_t)(n0 + ty + j * 8) * K + k0 + tx] = f2bf(tl[tx][ty + j * 8]);
        return;
    }
    if (bid < PREP_CB_END) {                   // ---- bias concat ----
        int i = (bid - PREP_W2_END) * 256 + tid;
        if (i < 2304)
            bqkv[i] = i < 768 ? bq[i] : (i < 1536 ? bk[i - 768] : bv[i - 1536]);
        return;
    }
    // ---- routing (single block) ----
    if (tid < 4) cnt[tid] = 0;
    __syncthreads();
    for (int t = tid; t < MB_TOK; t += 256) atomicAdd(&cnt[wl[t] & 3], 1);
    __syncthreads();
    if (tid == 0) {
        off[0] = 0;
        for (int e = 0; e < 4; ++e) off[e + 1] = off[e] + cnt[e];
        int idx = 0;
        for (int e = 0; e < 4; ++e)
            for (int s = 0; s < cnt[e]; s += 128)
                fmap[idx++] = make_int4(e, off[e], s, cnt[e] - s);
        for (; idx < 72; ++idx) fmap[idx] = make_int4(-1, 0, 0, 0);
        int idx2 = 0;
        for (int e = 0; e < 4; ++e)
            for (int s = 0; s < cnt[e]; s += 64)
                fmap64[idx2++] = make_int4(e, off[e], s, cnt[e] - s);
        for (; idx2 < 136; ++idx2) fmap64[idx2] = make_int4(-1, 0, 0, 0);
        for (int e = 0; e < 5; ++e) eoff[e] = off[e];
        for (int e = 0; e < 4; ++e) cur[e] = off[e];
    }
    __syncthreads();
    for (int t = tid; t < MB_TOK; t += 256) {
        int e = wl[t] & 3;
        int pos = atomicAdd(&cur[e], 1);
        perm[pos] = t;
    }
}

// ---------- V transpose: qkv bf16 V-cols -> vT[bh][d][key] ----------
__global__ __launch_bounds__(256) void vT_kernel(
    const u16* __restrict__ qkv, u16* __restrict__ vT)
{
    __shared__ u16 tl[32][33];
    int bh = blockIdx.z;
    int b = bh / HH, h = bh % HH;
    int key0 = blockIdx.x * 32;
    int d0 = blockIdx.y * 32;
    int tx = threadIdx.x & 31, ty = threadIdx.x >> 5;
    const u16* src = qkv + ((size_t)b * SEQ + key0) * 2304 + 1536 + h * 64 + d0;
    #pragma unroll
    for (int j = 0; j < 4; ++j)
        tl[ty + j * 8][tx] = src[(size_t)(ty + j * 8) * 2304 + tx];
    __syncthreads();
    u16* dst = vT + ((size_t)bh * 64 + d0) * SEQ + key0;
    #pragma unroll
    for (int j = 0; j < 4; ++j)
        dst[(size_t)(ty + j * 8) * SEQ + tx] = tl[tx][ty + j * 8];
}

// ---------- GEMM: C[M,N] = A[M,K](bf16) * Bt[N,K](bf16)^T + bias ----------
// MODE 0: dense. MODE 1: A rows via perm (FFN1). MODE 2: C rows via perm (FFN2).
// TM: M-tile (128 or 64). N-tile 128. BK=32. 2-buffer, stage-after-barrier.
// KS: split-K factor; KS>1 accumulates via f32 atomics (exactly KS commutative
// adds into a zeroed buffer -> deterministic), bias added by ks==0 only.
// XCD-chunked mapping: xcd = blockIdx&7 owns contiguous bt range, tn fastest.
template<int MODE, int TM, int KS, bool RELU, bool RES, bool ST32, bool ST16>
__global__ __launch_bounds__(256, (TM == 64) ? 6 : 5) void gemm_bt_kernel(
    const u16* __restrict__ A, const u16* __restrict__ Bt,
    const float* __restrict__ bias, const float* __restrict__ res,
    float* __restrict__ out32, u16* __restrict__ out16,
    int nbt, int N, int K, int ntn,
    const int* __restrict__ perm, const int4* __restrict__ fmap)
{
    constexpr int ALD = TM * 32;
    constexpr int NN  = (TM == 64) ? 2 : 4;    // n-frags per wave
    __shared__ __attribute__((aligned(16))) u16 As[2][ALD];
    __shared__ __attribute__((aligned(16))) u16 Bs[2][4096];
    int tid = threadIdx.x;
    int wv = tid >> 6, ln = tid & 63;
    int per = ntn * KS;
    int bpx = gridDim.x / (per << 3);
    int jj = blockIdx.x >> 3;
    int bt = (blockIdx.x & 7) * bpx + jj / per;
    int rem = jj % per;
    int tn = (rem % ntn) * 128;
    int ks = rem / ntn;
    if (bt >= nbt) return;

    int seg = 0, ms = 0, mb = TM, tm = 0;
    if (MODE != 0) {
        int4 ent = fmap[bt];
        if (ent.x < 0) return;
        seg = ent.y; ms = ent.z; mb = ent.w; if (mb > TM) mb = TM;
        Bt += (size_t)ent.x * N * K;
        bias += ent.x * N;
    } else {
        tm = bt * TM;
    }

    f32x4 acc[4][NN];
    #pragma unroll
    for (int i = 0; i < 4; ++i)
        #pragma unroll
        for (int j = 0; j < NN; ++j) acc[i][j] = f32x4{0.f, 0.f, 0.f, 0.f};

    int wr = (TM == 128) ? (wv >> 1) : 0;
    int wcol0 = (TM == 128) ? (wv & 1) * 64 : wv * 32;
    int lr = ln & 15, hi = ln >> 4;
    int nk = K / KS / 32;                      // rounds in this K-split
    int kbase = ks * (K / KS);

    // per-thread staging source bases (row const across K-steps)
    const u16* asrc[2];
    const u16* bsrc[2];
    #pragma unroll
    for (int i = 0; i < 2; ++i) {
        int rA = (TM == 128) ? ((wv * 2 + i) * 16 + (ln >> 2))
                             : (wv * 16 + (ln >> 2));
        if (TM == 128 || i == 0) {
            int am = rA < mb ? rA : (mb - 1);
            size_t arow;
            if (MODE == 1)      arow = (size_t)perm[seg + ms + am];
            else if (MODE == 2) arow = (size_t)(seg + ms + am);
            else                arow = (size_t)(tm + rA);
            asrc[i] = A + arow * K + kbase + (ln & 3) * 8;
        }
        int rB = (wv * 2 + i) * 16 + (ln >> 2);
        bsrc[i] = Bt + (size_t)(tn + rB) * K + kbase + (ln & 3) * 8;
    }
    int aofs0 = (TM == 128) ? (wv * 2) * 512 : wv * 512;

#define GSTAGE(bf_, k0_) do {                                             \
    gload_lds16(asrc[0] + (k0_), &As[bf_][aofs0]);                        \
    if (TM == 128) gload_lds16(asrc[1] + (k0_), &As[bf_][aofs0 + 512]);   \
    gload_lds16(bsrc[0] + (k0_), &Bs[bf_][(wv * 2) * 512]);               \
    gload_lds16(bsrc[1] + (k0_), &Bs[bf_][(wv * 2 + 1) * 512]);           \
} while (0)

    GSTAGE(0, 0);
    for (int kk = 0; kk < nk; ++kk) {
        int bf = kk & 1;
        __syncthreads();                       // buf[bf] ready (vmcnt drained)
        if (kk + 1 < nk) GSTAGE(bf ^ 1, (kk + 1) * 32);
        bf16x8 a[4], b[NN];
        #pragma unroll
        for (int m = 0; m < 4; ++m)
            a[m] = *(const bf16x8*)&As[bf][(wr * 64 + m * 16 + lr) * 32 + hi * 8];
        #pragma unroll
        for (int n = 0; n < NN; ++n)
            b[n] = *(const bf16x8*)&Bs[bf][(wcol0 + n * 16 + lr) * 32 + hi * 8];
        #pragma unroll
        for (int m = 0; m < 4; ++m)
            #pragma unroll
            for (int n = 0; n < NN; ++n)
                acc[m][n] = mfma16(a[m], b[n], acc[m][n]);
    }
#undef GSTAGE

    // epilogue: C/D layout col=lane&15, row=(lane>>4)*4+i
    #pragma unroll
    for (int m = 0; m < 4; ++m) {
        int rb = wr * 64 + m * 16 + hi * 4;
        #pragma unroll
        for (int n = 0; n < NN; ++n) {
            int gcol = tn + wcol0 + n * 16 + lr;
            float bvv = (KS > 1 && ks != 0) ? 0.f : bias[gcol];
            #pragma unroll
            for (int i = 0; i < 4; ++i) {
                int rml = rb + i;
                float v = acc[m][n][i] + bvv;
                if (RELU) v = v > 0.f ? v : 0.f;
                if (MODE == 0) {
                    size_t grow = (size_t)(tm + rml);
                    if (RES) v += res[grow * N + gcol];
                    if (ST32) out32[grow * N + gcol] = v;
                    if (ST16) out16[grow * N + gcol] = f2bf(v);
                } else {
                    if (rml < mb) {
                        size_t orow = (MODE == 1) ? (size_t)(seg + ms + rml)
                                                  : (size_t)perm[seg + ms + rml];
                        if (ST32) {
                            if (KS > 1) unsafeAtomicAdd(&out32[orow * N + gcol], v);
                            else        out32[orow * N + gcol] = v;
                        }
                        if (ST16) out16[orow * N + gcol] = f2bf(v);
                    }
                }
            }
        }
    }
}

// ---------- flash attention: 32x32 MFMA, 32 q/wave, double-buffered K/V ----------
__global__ __launch_bounds__(256, 4) void attn_kernel(
    const u16* __restrict__ qkv, const u16* __restrict__ vT,
    u16* __restrict__ ctx)
{
    __shared__ __attribute__((aligned(16))) u16 Ks[2][4096];
    __shared__ __attribute__((aligned(16))) u16 Vs[2][4096];
    int tid = threadIdx.x;
    int wv = tid >> 6, ln = tid & 63;
    int qv = ln & 31, hi = ln >> 5;
    int bid = blockIdx.x;
    int bh = (bid & 7) * 6 + ((bid >> 3) % 6);
    int qt = (bid >> 3) / 6;
    int b = bh / HH, h = bh % HH;
    int q0 = qt * 128 + wv * 32;
    size_t qrowb = (size_t)(b * SEQ + q0);
    const float C = 0.125f * LOG2E;

    bf16x8 qf[4];
    {
        const u16* qp = qkv + (qrowb + qv) * 2304 + h * 64 + hi * 8;
        #pragma unroll
        for (int ds = 0; ds < 4; ++ds) qf[ds] = *(const bf16x8*)(qp + ds * 16);
    }

    int csrc = 8 * ((ln & 7) ^ (ln >> 3));
    const size_t kbase = (size_t)b * SEQ * 2304 + 768 + h * 64;
    const u16* vtb = vT + (size_t)bh * 64 * SEQ;
    const u16* kp0 = qkv + kbase + (size_t)(wv * 16 + (ln >> 3)) * 2304 + csrc;
    const u16* kp1 = kp0 + (size_t)8 * 2304;
    const u16* vp0 = vtb + (size_t)(wv * 16 + (ln >> 3)) * SEQ + csrc;
    const u16* vp1 = vp0 + (size_t)8 * SEQ;

#define ATTN_STAGE(bf_, t_) do {                                          \
    gload_lds16(kp0 + (size_t)(t_) * 64 * 2304, &Ks[bf_][(wv * 2) * 512]);\
    gload_lds16(kp1 + (size_t)(t_) * 64 * 2304, &Ks[bf_][(wv * 2 + 1) * 512]);\
    gload_lds16(vp0 + (size_t)(t_) * 64, &Vs[bf_][(wv * 2) * 512]);       \
    gload_lds16(vp1 + (size_t)(t_) * 64, &Vs[bf_][(wv * 2 + 1) * 512]);   \
} while (0)

    f32x16 oacc[2];
    #pragma unroll
    for (int i = 0; i < 2; ++i)
        #pragma unroll
        for (int r = 0; r < 16; ++r) oacc[i][r] = 0.f;
    float m_run = -INFINITY, l_run = 0.f;
    int ksw = (qv & 7) * 8;

    ATTN_STAGE(0, 0);

    for (int kt = 0; kt < SEQ / 64; ++kt) {
        int bf = kt & 1;
        __syncthreads();
        if (kt + 1 < SEQ / 64) ATTN_STAGE(bf ^ 1, kt + 1);

        f32x16 s0, s1;
        #pragma unroll
        for (int r = 0; r < 16; ++r) { s0[r] = 0.f; s1[r] = 0.f; }
        #pragma unroll
        for (int ds = 0; ds < 4; ++ds) {
            bf16x8 ka0 = *(const bf16x8*)&Ks[bf][qv * 64 + ((ds * 16 + hi * 8) ^ ksw)];
            bf16x8 ka1 = *(const bf16x8*)&Ks[bf][(32 + qv) * 64 + ((ds * 16 + hi * 8) ^ ksw)];
            s0 = mfma32(ka0, qf[ds], s0);
            s1 = mfma32(ka1, qf[ds], s1);
        }

        float tmax = s0[0];
        #pragma unroll
        for (int r = 1; r < 16; ++r) tmax = fmaxf(tmax, s0[r]);
        #pragma unroll
        for (int r = 0; r < 16; ++r) tmax = fmaxf(tmax, s1[r]);
        tmax = fmaxf(tmax, __shfl_xor(tmax, 32));

        if (!__all(tmax - m_run <= 64.f)) {   // defer-max (T13), 8 nats
            float m_new = fmaxf(m_run, tmax);
            float corr = exp2_hw((m_run - m_new) * C);
            l_run *= corr;
            #pragma unroll
            for (int i = 0; i < 2; ++i)
                #pragma unroll
                for (int r = 0; r < 16; ++r) oacc[i][r] *= corr;
            m_run = m_new;
        }
        float c2 = -m_run * C;
        float psum = 0.f;
        #pragma unroll
        for (int r = 0; r < 16; ++r) {
            s0[r] = exp2_hw(fmaf(s0[r], C, c2)); psum += s0[r];
            s1[r] = exp2_hw(fmaf(s1[r], C, c2)); psum += s1[r];
        }
        l_run += psum;

        #pragma unroll
        for (int kb = 0; kb < 2; ++kb) {
            #pragma unroll
            for (int hc = 0; hc < 2; ++hc) {
                const f32x16& sv = kb ? s1 : s0;
                unsigned x0 = cvt_pk_bf16(sv[8 * hc + 0], sv[8 * hc + 1]);
                unsigned x1 = cvt_pk_bf16(sv[8 * hc + 2], sv[8 * hc + 3]);
                unsigned x2 = cvt_pk_bf16(sv[8 * hc + 4], sv[8 * hc + 5]);
                unsigned x3 = cvt_pk_bf16(sv[8 * hc + 6], sv[8 * hc + 7]);
                unsigned t0 = hi ? x0 : x2, t1 = hi ? x1 : x3;
                unsigned r0 = (unsigned)__shfl_xor((int)t0, 32);
                unsigned r1 = (unsigned)__shfl_xor((int)t1, 32);
                union { bf16x8 v; unsigned u[4]; } pf;
                pf.u[0] = hi ? r0 : x0; pf.u[1] = hi ? r1 : x1;
                pf.u[2] = hi ? x2 : r0; pf.u[3] = hi ? x3 : r1;
                int kc = (kb * 32 + hc * 16 + hi * 8) ^ ksw;
                #pragma unroll
                for (int dblk = 0; dblk < 2; ++dblk) {
                    bf16x8 va = *(const bf16x8*)&Vs[bf][(dblk * 32 + qv) * 64 + kc];
                    oacc[dblk] = mfma32(va, pf.v, oacc[dblk]);
                }
            }
        }
    }
#undef ATTN_STAGE

    float l_tot = l_run + __shfl_xor(l_run, 32);
    float inv = 1.f / l_tot;

    __syncthreads();
    u16* eb = &Ks[0][0] + wv * 2048;
    #pragma unroll
    for (int dblk = 0; dblk < 2; ++dblk)
        #pragma unroll
        for (int r = 0; r < 16; r += 2) {
            int d = dblk * 32 + (r & 3) + 8 * (r >> 2) + 4 * hi;
            unsigned pk = cvt_pk_bf16(oacc[dblk][r] * inv, oacc[dblk][r + 1] * inv);
            *(unsigned*)&eb[qv * 64 + (d ^ ((qv & 7) * 8))] = pk;
        }
    __syncthreads();
    {
        u16* ctr = ctx + (qrowb + qv) * DM + h * 64 + hi * 32;
        #pragma unroll
        for (int g = 0; g < 4; ++g) {
            bf16x8 vv = *(const bf16x8*)&eb[qv * 64 + ((hi * 32 + g * 8) ^ ((qv & 7) * 8))];
            *(bf16x8*)(ctr + g * 8) = vv;
        }
    }
}

// ---------- way classifier: logits = outb(bf16) @ wcls + bcls ----------
__global__ __launch_bounds__(256) void cls_kernel(
    const u16* __restrict__ outm, const float* __restrict__ wcls,
    const float* __restrict__ bcls, float* __restrict__ dst)
{
    int row = blockIdx.x, t = threadIdx.x;
    const u16* xr = outm + (size_t)row * DM;
    float a0 = 0, a1 = 0, a2 = 0, a3 = 0;
    for (int j = t; j < DM; j += 256) {
        float xv = bf2f(xr[j]);
        float4 wv4 = *(const float4*)(const void*)(wcls + (size_t)j * 4);
        a0 += xv * wv4.x; a1 += xv * wv4.y; a2 += xv * wv4.z; a3 += xv * wv4.w;
    }
    #pragma unroll
    for (int k = 1; k < 64; k <<= 1) {
        a0 += __shfl_xor(a0, k); a1 += __shfl_xor(a1, k);
        a2 += __shfl_xor(a2, k); a3 += __shfl_xor(a3, k);
    }
    __shared__ float red[4][4];
    if ((t & 63) == 0) {
        int wid = t >> 6;
        red[wid][0] = a0; red[wid][1] = a1; red[wid][2] = a2; red[wid][3] = a3;
    }
    __syncthreads();
    if (t < 4)
        dst[(size_t)row * 4 + t] =
            red[0][t] + red[1][t] + red[2][t] + red[3][t] + bcls[t];
}

// ---------- launch ----------
extern "C" void kernel_launch(void* const* d_in, const int* in_sizes, int n_in,
                              void* d_out, int out_size, void* d_ws, size_t ws_size,
                              hipStream_t stream) {
    const float* x      = (const float*)d_in[0];
    const int*   wl     = (const int*)d_in[1];        // int inputs are int32
    const float* ln_g   = (const float*)d_in[2];
    const float* ln_b   = (const float*)d_in[3];
    const float* wq     = (const float*)d_in[4];
    const float* bq     = (const float*)d_in[5];
    const float* wk     = (const float*)d_in[6];
    const float* bk     = (const float*)d_in[7];
    const float* wvv    = (const float*)d_in[8];
    const float* bv     = (const float*)d_in[9];
    const float* wo     = (const float*)d_in[10];
    const float* bo     = (const float*)d_in[11];
    const float* wcls   = (const float*)d_in[12];
    const float* bcls   = (const float*)d_in[13];
    const float* w1     = (const float*)d_in[14];
    const float* b1     = (const float*)d_in[15];
    const float* w2     = (const float*)d_in[16];
    const float* b2     = (const float*)d_in[17];
    float* out = (float*)d_out;

    char* ws = (char*)d_ws;
    u16*   xn    = (u16*)  (ws + 0);            // 12,582,912 B
    u16*   qkv   = (u16*)  (ws + 12582912);     // 37,748,736 B
    u16*   hbuf  = (u16*)  (ws + 0);            // reuse xn+qkv (50,331,648 B)
    u16*   ctx   = (u16*)  (ws + 50331648);     // 12,582,912
    u16*   outb  = (u16*)  (ws + 62914560);     // 12,582,912
    u16*   wqkvt = (u16*)  (ws + 75497472);     // 3,538,944
    u16*   wot   = (u16*)  (ws + 79036416);     // 1,179,648
    u16*   w1t   = (u16*)  (ws + 80216064);     // 18,874,368
    u16*   w2t   = (u16*)  (ws + 99090432);     // 18,874,368
    float* bqkv  = (float*)(ws + 117964800);    // 9,216
    int*   perm  = (int*)  (ws + 117974016);    // 32,768
    int*   eoff  = (int*)  (ws + 118006784);    // 32
    int4*  fmap  = (int4*) (ws + 118006816);    // 1,152 (72 entries)
    int4*  fmap64= (int4*) (ws + 118007968);    // 2,176 (136 entries)
    u16*   vT    = (u16*)  (ws + 118010144);    // 12,582,912 (16B aligned)

    // zero the FFN output region (split-K accumulates into it atomically)
    hipMemsetAsync(out, 0, (size_t)MB_TOK * DM * sizeof(float), stream);

    // fused prep: LN + weight transposes + bias concat + routing
    prep_kernel<<<PREP_GRID, 256, 0, stream>>>(
        x, ln_g, ln_b, xn, wq, wk, wvv, wo, wqkvt, wot,
        w1, w1t, w2, w2t, bq, bk, bv, bqkv, wl, perm, eoff, fmap, fmap64);

    // QKV: TM=128, grid = 8 xcd * 8 bt * 18 tn
    gemm_bt_kernel<0, 128, 1, false, false, false, true><<<1152, 256, 0, stream>>>(
        xn, wqkvt, bqkv, nullptr, nullptr, qkv, 64, 2304, 768, 18, nullptr, nullptr);

    // V transpose for attention PV operand
    vT_kernel<<<dim3(64, 2, 48), 256, 0, stream>>>(qkv, vT);

    attn_kernel<<<768, 256, 0, stream>>>(qkv, vT, ctx);

    // WO + residual -> outb (bf16)   TM=64, grid = 8*16*6
    gemm_bt_kernel<0, 64, 1, false, true, false, true><<<768, 256, 0, stream>>>(
        ctx, wot, bo, x, nullptr, outb, 128, 768, 768, 6, nullptr, nullptr);

    cls_kernel<<<MB_TOK, 256, 0, stream>>>(outb, wcls, bcls, out + (size_t)MB_TOK * DM);

    // FFN1: gathered rows, relu -> h   TM=128, grid = 8*9*24
    gemm_bt_kernel<1, 128, 1, true, false, false, true><<<1728, 256, 0, stream>>>(
        outb, w1t, b1, nullptr, nullptr, hbuf, 72, DFF, 768, 24, perm, fmap);

    // FFN2: h -> atomic-accumulate into d_out   TM=64 KS=2, grid = 8*17*12
    gemm_bt_kernel<2, 64, 2, false, false, true, false><<<1632, 256, 0, stream>>>(
        hbuf, w2t, b2, nullptr, out, nullptr, 136, 768, DFF, 6, perm, fmap64);
}

// Round 10
// 361.066 us; speedup vs baseline: 1.1543x; 1.1543x over previous
//
#include <hip/hip_runtime.h>
#include <cstdint>

typedef unsigned short u16;
typedef float f32x4 __attribute__((ext_vector_type(4)));
typedef float f32x16 __attribute__((ext_vector_type(16)));
typedef __bf16 bf16x8 __attribute__((ext_vector_type(8)));
typedef unsigned u32x4v __attribute__((ext_vector_type(4)));

#define LOG2E 1.44269504088896340736f

// ---------- helpers ----------
__device__ __forceinline__ u16 f2bf(float f) {
    union { float f; unsigned u; } v; v.f = f;
    unsigned r = v.u + 0x7fffu + ((v.u >> 16) & 1u);   // RNE
    return (u16)(r >> 16);
}

__device__ __forceinline__ float bf2f(u16 v) {
    union { unsigned u; float f; } x; x.u = ((unsigned)v) << 16; return x.f;
}

__device__ __forceinline__ unsigned cvt_pk_bf16(float lo, float hi) {
    unsigned r;
    asm("v_cvt_pk_bf16_f32 %0, %1, %2" : "=v"(r) : "v"(lo), "v"(hi));
    return r;
}

__device__ __forceinline__ float exp2_hw(float x) {
    float r;
    asm("v_exp_f32 %0, %1" : "=v"(r) : "v"(x));
    return r;
}

__device__ __forceinline__ f32x4 mfma16(bf16x8 a, bf16x8 b, f32x4 c) {
    return __builtin_amdgcn_mfma_f32_16x16x32_bf16(a, b, c, 0, 0, 0);
}

__device__ __forceinline__ f32x16 mfma32(bf16x8 a, bf16x8 b, f32x16 c) {
    return __builtin_amdgcn_mfma_f32_32x32x16_bf16(a, b, c, 0, 0, 0);
}

__device__ __forceinline__ void gload_lds16(const void* g, void* l) {
    __builtin_amdgcn_global_load_lds(
        (__attribute__((address_space(1))) unsigned int*)(g),
        (__attribute__((address_space(3))) unsigned int*)(l),
        16, 0, 0);
}

// LDS byte-offset of a __shared__ pointer (for inline-asm ds_read)
__device__ __forceinline__ unsigned lds_off(const void* p) {
    return (unsigned)(size_t)(__attribute__((address_space(3))) const void*)p;
}

// compiler-invisible LDS read: no auto vmcnt(0) insertion (rule #18 discipline)
__device__ __forceinline__ bf16x8 lds_read16(unsigned byte_off) {
    u32x4v r;
    asm volatile("ds_read_b128 %0, %1" : "=v"(r) : "v"(byte_off));
    union { u32x4v u; bf16x8 b; } c; c.u = r; return c.b;
}

// ---------- constants ----------
#define MB_TOK 8192      // B*S
#define DM 768
#define HH 12
#define DHD 64
#define NWAY 4
#define DFF 3072
#define SEQ 2048
#define NBATCH 4

// ---------- fused prep: LN + 6 weight transposes + bias concat + routing ----------
#define PREP_LN_END   8192
#define PREP_T7_END   10496
#define PREP_W1_END   19712
#define PREP_W2_END   28928
#define PREP_CB_END   28937
#define PREP_GRID     28938

__global__ __launch_bounds__(256) void prep_kernel(
    const float* __restrict__ x, const float* __restrict__ ln_g,
    const float* __restrict__ ln_b, u16* __restrict__ xn,
    const float* __restrict__ wq, const float* __restrict__ wk,
    const float* __restrict__ wvv, const float* __restrict__ wo,
    u16* __restrict__ wqkvt, u16* __restrict__ wot,
    const float* __restrict__ w1, u16* __restrict__ w1t,
    const float* __restrict__ w2, u16* __restrict__ w2t,
    const float* __restrict__ bq, const float* __restrict__ bk,
    const float* __restrict__ bv, float* __restrict__ bqkv,
    const int* __restrict__ wl, int* __restrict__ perm,
    int* __restrict__ eoff, int4* __restrict__ fmap, int4* __restrict__ fmap64)
{
    __shared__ float tl[32][33];
    __shared__ float red[4];
    __shared__ int cnt[4], cur[4], off[5];
    int bid = blockIdx.x, tid = threadIdx.x;

    if (bid < PREP_LN_END) {                   // ---- LayerNorm row ----
        int row = bid;
        const float* xr = x + (size_t)row * DM;
        float v0 = xr[tid], v1 = xr[tid + 256], v2 = xr[tid + 512];
        float s = v0 + v1 + v2;
        #pragma unroll
        for (int k = 1; k < 64; k <<= 1) s += __shfl_xor(s, k);
        if ((tid & 63) == 0) red[tid >> 6] = s;
        __syncthreads();
        float mu = (red[0] + red[1] + red[2] + red[3]) * (1.f / 768.f);
        float d0 = v0 - mu, d1 = v1 - mu, d2 = v2 - mu;
        float q = d0 * d0 + d1 * d1 + d2 * d2;
        #pragma unroll
        for (int k = 1; k < 64; k <<= 1) q += __shfl_xor(q, k);
        __syncthreads();
        if ((tid & 63) == 0) red[tid >> 6] = q;
        __syncthreads();
        float var = (red[0] + red[1] + red[2] + red[3]) * (1.f / 768.f);
        float rs = rsqrtf(var + 1e-6f);
        u16* xo = xn + (size_t)row * DM;
        xo[tid]       = f2bf(d0 * rs * ln_g[tid]       + ln_b[tid]);
        xo[tid + 256] = f2bf(d1 * rs * ln_g[tid + 256] + ln_b[tid + 256]);
        xo[tid + 512] = f2bf(d2 * rs * ln_g[tid + 512] + ln_b[tid + 512]);
        return;
    }
    if (bid < PREP_W2_END) {                   // ---- weight transposes ----
        const float* src; u16* dst; int K, N, n0, k0;
        if (bid < PREP_T7_END) {
            int r = bid - PREP_LN_END;
            int wsel = r / 576, lb = r % 576;
            K = 768; N = 768;
            n0 = (lb % 24) * 32; k0 = (lb / 24) * 32;
            src = wsel == 0 ? wq : (wsel == 1 ? wk : (wsel == 2 ? wvv : wo));
            dst = wsel == 3 ? wot : (wqkvt + (size_t)wsel * 768 * 768);
        } else if (bid < PREP_W1_END) {
            int lb = bid - PREP_T7_END;
            K = 768; N = 3072;
            n0 = (lb % 96) * 32; k0 = ((lb / 96) % 24) * 32;
            int z = lb / 2304;
            src = w1 + (size_t)z * K * N; dst = w1t + (size_t)z * K * N;
        } else {
            int lb = bid - PREP_W1_END;
            K = 3072; N = 768;
            n0 = (lb % 24) * 32; k0 = ((lb / 24) % 96) * 32;
            int z = lb / 2304;
            src = w2 + (size_t)z * K * N; dst = w2t + (size_t)z * K * N;
        }
        int tx = tid & 31, ty = tid >> 5;
        #pragma unroll
        for (int j = 0; j < 4; ++j)
            tl[ty + j * 8][tx] = src[(size_t)(k0 + ty + j * 8) * N + n0 + tx];
        __syncthreads();
        #pragma unroll
        for (int j = 0; j < 4; ++j)
            dst[(size_t)(n0 + ty + j * 8) * K + k0 + tx] = f2bf(tl[tx][ty + j * 8]);
        return;
    }
    if (bid < PREP_CB_END) {                   // ---- bias concat ----
        int i = (bid - PREP_W2_END) * 256 + tid;
        if (i < 2304)
            bqkv[i] = i < 768 ? bq[i] : (i < 1536 ? bk[i - 768] : bv[i - 1536]);
        return;
    }
    // ---- routing (single block) ----
    if (tid < 4) cnt[tid] = 0;
    __syncthreads();
    for (int t = tid; t < MB_TOK; t += 256) atomicAdd(&cnt[wl[t] & 3], 1);
    __syncthreads();
    if (tid == 0) {
        off[0] = 0;
        for (int e = 0; e < 4; ++e) off[e + 1] = off[e] + cnt[e];
        int idx = 0;
        for (int e = 0; e < 4; ++e)
            for (int s = 0; s < cnt[e]; s += 128)
                fmap[idx++] = make_int4(e, off[e], s, cnt[e] - s);
        for (; idx < 72; ++idx) fmap[idx] = make_int4(-1, 0, 0, 0);
        int idx2 = 0;
        for (int e = 0; e < 4; ++e)
            for (int s = 0; s < cnt[e]; s += 64)
                fmap64[idx2++] = make_int4(e, off[e], s, cnt[e] - s);
        for (; idx2 < 136; ++idx2) fmap64[idx2] = make_int4(-1, 0, 0, 0);
        for (int e = 0; e < 5; ++e) eoff[e] = off[e];
        for (int e = 0; e < 4; ++e) cur[e] = off[e];
    }
    __syncthreads();
    for (int t = tid; t < MB_TOK; t += 256) {
        int e = wl[t] & 3;
        int pos = atomicAdd(&cur[e], 1);
        perm[pos] = t;
    }
}

// ---------- V transpose: qkv bf16 V-cols -> vT[bh][d][key] ----------
__global__ __launch_bounds__(256) void vT_kernel(
    const u16* __restrict__ qkv, u16* __restrict__ vT)
{
    __shared__ u16 tl[32][33];
    int bh = blockIdx.z;
    int b = bh / HH, h = bh % HH;
    int key0 = blockIdx.x * 32;
    int d0 = blockIdx.y * 32;
    int tx = threadIdx.x & 31, ty = threadIdx.x >> 5;
    const u16* src = qkv + ((size_t)b * SEQ + key0) * 2304 + 1536 + h * 64 + d0;
    #pragma unroll
    for (int j = 0; j < 4; ++j)
        tl[ty + j * 8][tx] = src[(size_t)(ty + j * 8) * 2304 + tx];
    __syncthreads();
    u16* dst = vT + ((size_t)bh * 64 + d0) * SEQ + key0;
    #pragma unroll
    for (int j = 0; j < 4; ++j)
        dst[(size_t)(ty + j * 8) * SEQ + tx] = tl[tx][ty + j * 8];
}

// ---------- GEMM: C[M,N] = A[M,K](bf16) * Bt[N,K](bf16)^T + bias ----------
// MODE 0: dense. MODE 1: A rows via perm (FFN1). MODE 2: C rows via perm (FFN2).
// TM: M-tile (128 or 64). N-tile 128. BK=32.
// 3-buffer prefetch-distance-2 pipeline: per-wave counted vmcnt(NLD) before
// s_barrier certifies each wave's own stage-k loads; barrier aggregates to
// block-wide. LDS reads are inline-asm ds_read_b128 (compiler-invisible, so
// no conservative vmcnt(0) is inserted); own lgkmcnt(0)+sched_barrier(0)
// fences per rule #18. XCD-chunked block mapping as before.
template<int MODE, int TM, bool RELU, bool RES, bool ST32, bool ST16>
__global__ __launch_bounds__(256, (TM == 64) ? 4 : 3) void gemm_bt_kernel(
    const u16* __restrict__ A, const u16* __restrict__ Bt,
    const float* __restrict__ bias, const float* __restrict__ res,
    float* __restrict__ out32, u16* __restrict__ out16,
    int nbt, int N, int K, int ntn,
    const int* __restrict__ perm, const int4* __restrict__ fmap)
{
    constexpr int ALD = TM * 32;               // u16 per A buffer
    constexpr int NN  = (TM == 64) ? 2 : 4;    // n-frags per wave
    constexpr int NLD = (TM == 128) ? 4 : 3;   // gload_lds per wave per stage
    __shared__ __attribute__((aligned(16))) u16 As[3][ALD];
    __shared__ __attribute__((aligned(16))) u16 Bs[3][4096];
    int tid = threadIdx.x;
    int wv = tid >> 6, ln = tid & 63;
    int bpx = gridDim.x / (ntn << 3);
    int jj = blockIdx.x >> 3;
    int bt = (blockIdx.x & 7) * bpx + jj / ntn;
    int tn = (jj % ntn) * 128;
    if (bt >= nbt) return;

    int seg = 0, ms = 0, mb = TM, tm = 0;
    if (MODE != 0) {
        int4 ent = fmap[bt];
        if (ent.x < 0) return;
        seg = ent.y; ms = ent.z; mb = ent.w; if (mb > TM) mb = TM;
        Bt += (size_t)ent.x * N * K;
        bias += ent.x * N;
    } else {
        tm = bt * TM;
    }

    f32x4 acc[4][NN];
    #pragma unroll
    for (int i = 0; i < 4; ++i)
        #pragma unroll
        for (int j = 0; j < NN; ++j) acc[i][j] = f32x4{0.f, 0.f, 0.f, 0.f};

    int wr = (TM == 128) ? (wv >> 1) : 0;
    int wcol0 = (TM == 128) ? (wv & 1) * 64 : wv * 32;
    int lr = ln & 15, hi = ln >> 4;
    int nk = K / 32;

    // per-thread staging source bases (row const across K-steps)
    const u16* asrc[2];
    const u16* bsrc[2];
    #pragma unroll
    for (int i = 0; i < 2; ++i) {
        int rA = (TM == 128) ? ((wv * 2 + i) * 16 + (ln >> 2))
                             : (wv * 16 + (ln >> 2));
        if (TM == 128 || i == 0) {
            int am = rA < mb ? rA : (mb - 1);
            size_t arow;
            if (MODE == 1)      arow = (size_t)perm[seg + ms + am];
            else if (MODE == 2) arow = (size_t)(seg + ms + am);
            else                arow = (size_t)(tm + rA);
            asrc[i] = A + arow * K + (ln & 3) * 8;
        }
        int rB = (wv * 2 + i) * 16 + (ln >> 2);
        bsrc[i] = Bt + (size_t)(tn + rB) * K + (ln & 3) * 8;
    }
    int aofs0 = (TM == 128) ? (wv * 2) * 512 : wv * 512;

    // LDS byte offsets for asm reads
    unsigned abase = lds_off(&As[0][0]);
    unsigned bbase = lds_off(&Bs[0][0]);
    unsigned aro = (unsigned)(((wr * 64 + lr) * 32 + hi * 8) * 2);
    unsigned bro = (unsigned)(((wcol0 + lr) * 32 + hi * 8) * 2);

#define GSTAGE(b_, k0_) do {                                              \
    gload_lds16(asrc[0] + (k0_), &As[b_][aofs0]);                         \
    if (TM == 128) gload_lds16(asrc[1] + (k0_), &As[b_][aofs0 + 512]);    \
    gload_lds16(bsrc[0] + (k0_), &Bs[b_][(wv * 2) * 512]);                \
    gload_lds16(bsrc[1] + (k0_), &Bs[b_][(wv * 2 + 1) * 512]);            \
} while (0)

    GSTAGE(0, 0);
    GSTAGE(1, 32);
    int bf3 = 0;
    for (int kk = 0; kk < nk; ++kk) {
        // per-wave: own stage-kk loads done; stage-kk+1's NLD may stay in flight
        if (kk + 1 < nk)
            asm volatile("s_waitcnt vmcnt(%0)" :: "i"(NLD) : "memory");
        else
            asm volatile("s_waitcnt vmcnt(0)" ::: "memory");
        __builtin_amdgcn_s_barrier();           // aggregate: buf[kk] block-valid
        __builtin_amdgcn_sched_barrier(0);
        if (kk + 2 < nk) {
            int nb = bf3 + 2; if (nb >= 3) nb -= 3;
            GSTAGE(nb, (kk + 2) * 32);
        }
        unsigned ab = abase + (unsigned)(bf3 * (ALD * 2)) + aro;
        unsigned bb = bbase + (unsigned)(bf3 * 8192) + bro;
        bf16x8 a[4], b[NN];
        #pragma unroll
        for (int m = 0; m < 4; ++m) a[m] = lds_read16(ab + m * 1024);
        #pragma unroll
        for (int n = 0; n < NN; ++n) b[n] = lds_read16(bb + n * 1024);
        asm volatile("s_waitcnt lgkmcnt(0)" ::: "memory");
        __builtin_amdgcn_sched_barrier(0);
        #pragma unroll
        for (int m = 0; m < 4; ++m)
            #pragma unroll
            for (int n = 0; n < NN; ++n)
                acc[m][n] = mfma16(a[m], b[n], acc[m][n]);
        bf3 = (bf3 == 2) ? 0 : bf3 + 1;
    }
#undef GSTAGE

    // epilogue: C/D layout col=lane&15, row=(lane>>4)*4+i
    #pragma unroll
    for (int m = 0; m < 4; ++m) {
        int rb = wr * 64 + m * 16 + hi * 4;
        #pragma unroll
        for (int n = 0; n < NN; ++n) {
            int gcol = tn + wcol0 + n * 16 + lr;
            float bvv = bias[gcol];
            #pragma unroll
            for (int i = 0; i < 4; ++i) {
                int rml = rb + i;
                float v = acc[m][n][i] + bvv;
                if (RELU) v = v > 0.f ? v : 0.f;
                if (MODE == 0) {
                    size_t grow = (size_t)(tm + rml);
                    if (RES) v += res[grow * N + gcol];
                    if (ST32) out32[grow * N + gcol] = v;
                    if (ST16) out16[grow * N + gcol] = f2bf(v);
                } else {
                    if (rml < mb) {
                        size_t orow = (MODE == 1) ? (size_t)(seg + ms + rml)
                                                  : (size_t)perm[seg + ms + rml];
                        if (ST32) out32[orow * N + gcol] = v;
                        if (ST16) out16[orow * N + gcol] = f2bf(v);
                    }
                }
            }
        }
    }
}

// ---------- flash attention: 32x32 MFMA, 32 q/wave, double-buffered K/V ----------
__global__ __launch_bounds__(256, 4) void attn_kernel(
    const u16* __restrict__ qkv, const u16* __restrict__ vT,
    u16* __restrict__ ctx)
{
    __shared__ __attribute__((aligned(16))) u16 Ks[2][4096];
    __shared__ __attribute__((aligned(16))) u16 Vs[2][4096];
    int tid = threadIdx.x;
    int wv = tid >> 6, ln = tid & 63;
    int qv = ln & 31, hi = ln >> 5;
    int bid = blockIdx.x;
    int bh = (bid & 7) * 6 + ((bid >> 3) % 6);
    int qt = (bid >> 3) / 6;
    int b = bh / HH, h = bh % HH;
    int q0 = qt * 128 + wv * 32;
    size_t qrowb = (size_t)(b * SEQ + q0);
    const float C = 0.125f * LOG2E;

    bf16x8 qf[4];
    {
        const u16* qp = qkv + (qrowb + qv) * 2304 + h * 64 + hi * 8;
        #pragma unroll
        for (int ds = 0; ds < 4; ++ds) qf[ds] = *(const bf16x8*)(qp + ds * 16);
    }

    int csrc = 8 * ((ln & 7) ^ (ln >> 3));
    const size_t kbase = (size_t)b * SEQ * 2304 + 768 + h * 64;
    const u16* vtb = vT + (size_t)bh * 64 * SEQ;
    const u16* kp0 = qkv + kbase + (size_t)(wv * 16 + (ln >> 3)) * 2304 + csrc;
    const u16* kp1 = kp0 + (size_t)8 * 2304;
    const u16* vp0 = vtb + (size_t)(wv * 16 + (ln >> 3)) * SEQ + csrc;
    const u16* vp1 = vp0 + (size_t)8 * SEQ;

#define ATTN_STAGE(bf_, t_) do {                                          \
    gload_lds16(kp0 + (size_t)(t_) * 64 * 2304, &Ks[bf_][(wv * 2) * 512]);\
    gload_lds16(kp1 + (size_t)(t_) * 64 * 2304, &Ks[bf_][(wv * 2 + 1) * 512]);\
    gload_lds16(vp0 + (size_t)(t_) * 64, &Vs[bf_][(wv * 2) * 512]);       \
    gload_lds16(vp1 + (size_t)(t_) * 64, &Vs[bf_][(wv * 2 + 1) * 512]);   \
} while (0)

    f32x16 oacc[2];
    #pragma unroll
    for (int i = 0; i < 2; ++i)
        #pragma unroll
        for (int r = 0; r < 16; ++r) oacc[i][r] = 0.f;
    float m_run = -INFINITY, l_run = 0.f;
    int ksw = (qv & 7) * 8;

    ATTN_STAGE(0, 0);

    for (int kt = 0; kt < SEQ / 64; ++kt) {
        int bf = kt & 1;
        __syncthreads();
        if (kt + 1 < SEQ / 64) ATTN_STAGE(bf ^ 1, kt + 1);

        f32x16 s0, s1;
        #pragma unroll
        for (int r = 0; r < 16; ++r) { s0[r] = 0.f; s1[r] = 0.f; }
        #pragma unroll
        for (int ds = 0; ds < 4; ++ds) {
            bf16x8 ka0 = *(const bf16x8*)&Ks[bf][qv * 64 + ((ds * 16 + hi * 8) ^ ksw)];
            bf16x8 ka1 = *(const bf16x8*)&Ks[bf][(32 + qv) * 64 + ((ds * 16 + hi * 8) ^ ksw)];
            s0 = mfma32(ka0, qf[ds], s0);
            s1 = mfma32(ka1, qf[ds], s1);
        }

        float tmax = s0[0];
        #pragma unroll
        for (int r = 1; r < 16; ++r) tmax = fmaxf(tmax, s0[r]);
        #pragma unroll
        for (int r = 0; r < 16; ++r) tmax = fmaxf(tmax, s1[r]);
        tmax = fmaxf(tmax, __shfl_xor(tmax, 32));

        if (!__all(tmax - m_run <= 64.f)) {   // defer-max (T13), 8 nats
            float m_new = fmaxf(m_run, tmax);
            float corr = exp2_hw((m_run - m_new) * C);
            l_run *= corr;
            #pragma unroll
            for (int i = 0; i < 2; ++i)
                #pragma unroll
                for (int r = 0; r < 16; ++r) oacc[i][r] *= corr;
            m_run = m_new;
        }
        float c2 = -m_run * C;
        float psum = 0.f;
        #pragma unroll
        for (int r = 0; r < 16; ++r) {
            s0[r] = exp2_hw(fmaf(s0[r], C, c2)); psum += s0[r];
            s1[r] = exp2_hw(fmaf(s1[r], C, c2)); psum += s1[r];
        }
        l_run += psum;

        #pragma unroll
        for (int kb = 0; kb < 2; ++kb) {
            #pragma unroll
            for (int hc = 0; hc < 2; ++hc) {
                const f32x16& sv = kb ? s1 : s0;
                unsigned x0 = cvt_pk_bf16(sv[8 * hc + 0], sv[8 * hc + 1]);
                unsigned x1 = cvt_pk_bf16(sv[8 * hc + 2], sv[8 * hc + 3]);
                unsigned x2 = cvt_pk_bf16(sv[8 * hc + 4], sv[8 * hc + 5]);
                unsigned x3 = cvt_pk_bf16(sv[8 * hc + 6], sv[8 * hc + 7]);
                unsigned t0 = hi ? x0 : x2, t1 = hi ? x1 : x3;
                unsigned r0 = (unsigned)__shfl_xor((int)t0, 32);
                unsigned r1 = (unsigned)__shfl_xor((int)t1, 32);
                union { bf16x8 v; unsigned u[4]; } pf;
                pf.u[0] = hi ? r0 : x0; pf.u[1] = hi ? r1 : x1;
                pf.u[2] = hi ? x2 : r0; pf.u[3] = hi ? x3 : r1;
                int kc = (kb * 32 + hc * 16 + hi * 8) ^ ksw;
                #pragma unroll
                for (int dblk = 0; dblk < 2; ++dblk) {
                    bf16x8 va = *(const bf16x8*)&Vs[bf][(dblk * 32 + qv) * 64 + kc];
                    oacc[dblk] = mfma32(va, pf.v, oacc[dblk]);
                }
            }
        }
    }
#undef ATTN_STAGE

    float l_tot = l_run + __shfl_xor(l_run, 32);
    float inv = 1.f / l_tot;

    __syncthreads();
    u16* eb = &Ks[0][0] + wv * 2048;
    #pragma unroll
    for (int dblk = 0; dblk < 2; ++dblk)
        #pragma unroll
        for (int r = 0; r < 16; r += 2) {
            int d = dblk * 32 + (r & 3) + 8 * (r >> 2) + 4 * hi;
            unsigned pk = cvt_pk_bf16(oacc[dblk][r] * inv, oacc[dblk][r + 1] * inv);
            *(unsigned*)&eb[qv * 64 + (d ^ ((qv & 7) * 8))] = pk;
        }
    __syncthreads();
    {
        u16* ctr = ctx + (qrowb + qv) * DM + h * 64 + hi * 32;
        #pragma unroll
        for (int g = 0; g < 4; ++g) {
            bf16x8 vv = *(const bf16x8*)&eb[qv * 64 + ((hi * 32 + g * 8) ^ ((qv & 7) * 8))];
            *(bf16x8*)(ctr + g * 8) = vv;
        }
    }
}

// ---------- way classifier: logits = outb(bf16) @ wcls + bcls ----------
__global__ __launch_bounds__(256) void cls_kernel(
    const u16* __restrict__ outm, const float* __restrict__ wcls,
    const float* __restrict__ bcls, float* __restrict__ dst)
{
    int row = blockIdx.x, t = threadIdx.x;
    const u16* xr = outm + (size_t)row * DM;
    float a0 = 0, a1 = 0, a2 = 0, a3 = 0;
    for (int j = t; j < DM; j += 256) {
        float xv = bf2f(xr[j]);
        float4 wv4 = *(const float4*)(const void*)(wcls + (size_t)j * 4);
        a0 += xv * wv4.x; a1 += xv * wv4.y; a2 += xv * wv4.z; a3 += xv * wv4.w;
    }
    #pragma unroll
    for (int k = 1; k < 64; k <<= 1) {
        a0 += __shfl_xor(a0, k); a1 += __shfl_xor(a1, k);
        a2 += __shfl_xor(a2, k); a3 += __shfl_xor(a3, k);
    }
    __shared__ float red[4][4];
    if ((t & 63) == 0) {
        int wid = t >> 6;
        red[wid][0] = a0; red[wid][1] = a1; red[wid][2] = a2; red[wid][3] = a3;
    }
    __syncthreads();
    if (t < 4)
        dst[(size_t)row * 4 + t] =
            red[0][t] + red[1][t] + red[2][t] + red[3][t] + bcls[t];
}

// ---------- launch ----------
extern "C" void kernel_launch(void* const* d_in, const int* in_sizes, int n_in,
                              void* d_out, int out_size, void* d_ws, size_t ws_size,
                              hipStream_t stream) {
    const float* x      = (const float*)d_in[0];
    const int*   wl     = (const int*)d_in[1];        // int inputs are int32
    const float* ln_g   = (const float*)d_in[2];
    const float* ln_b   = (const float*)d_in[3];
    const float* wq     = (const float*)d_in[4];
    const float* bq     = (const float*)d_in[5];
    const float* wk     = (const float*)d_in[6];
    const float* bk     = (const float*)d_in[7];
    const float* wvv    = (const float*)d_in[8];
    const float* bv     = (const float*)d_in[9];
    const float* wo     = (const float*)d_in[10];
    const float* bo     = (const float*)d_in[11];
    const float* wcls   = (const float*)d_in[12];
    const float* bcls   = (const float*)d_in[13];
    const float* w1     = (const float*)d_in[14];
    const float* b1     = (const float*)d_in[15];
    const float* w2     = (const float*)d_in[16];
    const float* b2     = (const float*)d_in[17];
    float* out = (float*)d_out;

    char* ws = (char*)d_ws;
    u16*   xn    = (u16*)  (ws + 0);            // 12,582,912 B
    u16*   qkv   = (u16*)  (ws + 12582912);     // 37,748,736 B
    u16*   hbuf  = (u16*)  (ws + 0);            // reuse xn+qkv (50,331,648 B)
    u16*   ctx   = (u16*)  (ws + 50331648);     // 12,582,912
    u16*   outb  = (u16*)  (ws + 62914560);     // 12,582,912
    u16*   wqkvt = (u16*)  (ws + 75497472);     // 3,538,944
    u16*   wot   = (u16*)  (ws + 79036416);     // 1,179,648
    u16*   w1t   = (u16*)  (ws + 80216064);     // 18,874,368
    u16*   w2t   = (u16*)  (ws + 99090432);     // 18,874,368
    float* bqkv  = (float*)(ws + 117964800);    // 9,216
    int*   perm  = (int*)  (ws + 117974016);    // 32,768
    int*   eoff  = (int*)  (ws + 118006784);    // 32
    int4*  fmap  = (int4*) (ws + 118006816);    // 1,152 (72 entries)
    int4*  fmap64= (int4*) (ws + 118007968);    // 2,176 (136 entries)
    u16*   vT    = (u16*)  (ws + 118010144);    // 12,582,912 (16B aligned)

    // fused prep: LN + weight transposes + bias concat + routing
    prep_kernel<<<PREP_GRID, 256, 0, stream>>>(
        x, ln_g, ln_b, xn, wq, wk, wvv, wo, wqkvt, wot,
        w1, w1t, w2, w2t, bq, bk, bv, bqkv, wl, perm, eoff, fmap, fmap64);

    // QKV: TM=128, grid = 8 xcd * 8 bt * 18 tn
    gemm_bt_kernel<0, 128, false, false, false, true><<<1152, 256, 0, stream>>>(
        xn, wqkvt, bqkv, nullptr, nullptr, qkv, 64, 2304, 768, 18, nullptr, nullptr);

    // V transpose for attention PV operand
    vT_kernel<<<dim3(64, 2, 48), 256, 0, stream>>>(qkv, vT);

    attn_kernel<<<768, 256, 0, stream>>>(qkv, vT, ctx);

    // WO + residual -> outb (bf16)   TM=64, grid = 8*16*6
    gemm_bt_kernel<0, 64, false, true, false, true><<<768, 256, 0, stream>>>(
        ctx, wot, bo, x, nullptr, outb, 128, 768, 768, 6, nullptr, nullptr);

    cls_kernel<<<MB_TOK, 256, 0, stream>>>(outb, wcls, bcls, out + (size_t)MB_TOK * DM);

    // FFN1: gathered rows, relu -> h   TM=128, grid = 8*9*24
    gemm_bt_kernel<1, 128, true, false, false, true><<<1728, 256, 0, stream>>>(
        outb, w1t, b1, nullptr, nullptr, hbuf, 72, DFF, 768, 24, perm, fmap);

    // FFN2: h -> scatter into d_out   TM=64, grid = 8*17*6
    gemm_bt_kernel<2, 64, false, false, true, false><<<816, 256, 0, stream>>>(
        hbuf, w2t, b2, nullptr, out, nullptr, 136, 768, DFF, 6, perm, fmap64);
}

// Round 11
// 347.368 us; speedup vs baseline: 1.1998x; 1.0394x over previous
//
#include <hip/hip_runtime.h>
#include <cstdint>

typedef unsigned short u16;
typedef float f32x4 __attribute__((ext_vector_type(4)));
typedef float f32x16 __attribute__((ext_vector_type(16)));
typedef __bf16 bf16x8 __attribute__((ext_vector_type(8)));

#define LOG2E 1.44269504088896340736f

// ---------- helpers ----------
__device__ __forceinline__ u16 f2bf(float f) {
    union { float f; unsigned u; } v; v.f = f;
    unsigned r = v.u + 0x7fffu + ((v.u >> 16) & 1u);   // RNE
    return (u16)(r >> 16);
}

__device__ __forceinline__ float bf2f(u16 v) {
    union { unsigned u; float f; } x; x.u = ((unsigned)v) << 16; return x.f;
}

__device__ __forceinline__ unsigned cvt_pk_bf16(float lo, float hi) {
    unsigned r;
    asm("v_cvt_pk_bf16_f32 %0, %1, %2" : "=v"(r) : "v"(lo), "v"(hi));
    return r;
}

__device__ __forceinline__ float exp2_hw(float x) {
    float r;
    asm("v_exp_f32 %0, %1" : "=v"(r) : "v"(x));
    return r;
}

__device__ __forceinline__ f32x4 mfma16(bf16x8 a, bf16x8 b, f32x4 c) {
    return __builtin_amdgcn_mfma_f32_16x16x32_bf16(a, b, c, 0, 0, 0);
}

__device__ __forceinline__ f32x16 mfma32(bf16x8 a, bf16x8 b, f32x16 c) {
    return __builtin_amdgcn_mfma_f32_32x32x16_bf16(a, b, c, 0, 0, 0);
}

__device__ __forceinline__ void gload_lds16(const void* g, void* l) {
    __builtin_amdgcn_global_load_lds(
        (__attribute__((address_space(1))) unsigned int*)(g),
        (__attribute__((address_space(3))) unsigned int*)(l),
        16, 0, 0);
}

// ---------- constants ----------
#define MB_TOK 8192      // B*S
#define DM 768
#define HH 12
#define DHD 64
#define NWAY 4
#define DFF 3072
#define SEQ 2048
#define NBATCH 4

// ---------- fused prep: LN + 6 weight transposes + bias concat + routing ----------
#define PREP_LN_END   8192
#define PREP_T7_END   10496
#define PREP_W1_END   19712
#define PREP_W2_END   28928
#define PREP_CB_END   28937
#define PREP_GRID     28938

__global__ __launch_bounds__(256) void prep_kernel(
    const float* __restrict__ x, const float* __restrict__ ln_g,
    const float* __restrict__ ln_b, u16* __restrict__ xn,
    const float* __restrict__ wq, const float* __restrict__ wk,
    const float* __restrict__ wvv, const float* __restrict__ wo,
    u16* __restrict__ wqkvt, u16* __restrict__ wot,
    const float* __restrict__ w1, u16* __restrict__ w1t,
    const float* __restrict__ w2, u16* __restrict__ w2t,
    const float* __restrict__ bq, const float* __restrict__ bk,
    const float* __restrict__ bv, float* __restrict__ bqkv,
    const int* __restrict__ wl, int* __restrict__ perm,
    int* __restrict__ eoff, int4* __restrict__ fmap, int4* __restrict__ fmap64)
{
    __shared__ float tl[32][33];
    __shared__ float red[4];
    __shared__ int cnt[4], cur[4], off[5];
    int bid = blockIdx.x, tid = threadIdx.x;

    if (bid < PREP_LN_END) {                   // ---- LayerNorm row ----
        int row = bid;
        const float* xr = x + (size_t)row * DM;
        float v0 = xr[tid], v1 = xr[tid + 256], v2 = xr[tid + 512];
        float s = v0 + v1 + v2;
        #pragma unroll
        for (int k = 1; k < 64; k <<= 1) s += __shfl_xor(s, k);
        if ((tid & 63) == 0) red[tid >> 6] = s;
        __syncthreads();
        float mu = (red[0] + red[1] + red[2] + red[3]) * (1.f / 768.f);
        float d0 = v0 - mu, d1 = v1 - mu, d2 = v2 - mu;
        float q = d0 * d0 + d1 * d1 + d2 * d2;
        #pragma unroll
        for (int k = 1; k < 64; k <<= 1) q += __shfl_xor(q, k);
        __syncthreads();
        if ((tid & 63) == 0) red[tid >> 6] = q;
        __syncthreads();
        float var = (red[0] + red[1] + red[2] + red[3]) * (1.f / 768.f);
        float rs = rsqrtf(var + 1e-6f);
        u16* xo = xn + (size_t)row * DM;
        xo[tid]       = f2bf(d0 * rs * ln_g[tid]       + ln_b[tid]);
        xo[tid + 256] = f2bf(d1 * rs * ln_g[tid + 256] + ln_b[tid + 256]);
        xo[tid + 512] = f2bf(d2 * rs * ln_g[tid + 512] + ln_b[tid + 512]);
        return;
    }
    if (bid < PREP_W2_END) {                   // ---- weight transposes ----
        const float* src; u16* dst; int K, N, n0, k0;
        if (bid < PREP_T7_END) {
            int r = bid - PREP_LN_END;
            int wsel = r / 576, lb = r % 576;
            K = 768; N = 768;
            n0 = (lb % 24) * 32; k0 = (lb / 24) * 32;
            src = wsel == 0 ? wq : (wsel == 1 ? wk : (wsel == 2 ? wvv : wo));
            dst = wsel == 3 ? wot : (wqkvt + (size_t)wsel * 768 * 768);
        } else if (bid < PREP_W1_END) {
            int lb = bid - PREP_T7_END;
            K = 768; N = 3072;
            n0 = (lb % 96) * 32; k0 = ((lb / 96) % 24) * 32;
            int z = lb / 2304;
            src = w1 + (size_t)z * K * N; dst = w1t + (size_t)z * K * N;
        } else {
            int lb = bid - PREP_W1_END;
            K = 3072; N = 768;
            n0 = (lb % 24) * 32; k0 = ((lb / 24) % 96) * 32;
            int z = lb / 2304;
            src = w2 + (size_t)z * K * N; dst = w2t + (size_t)z * K * N;
        }
        int tx = tid & 31, ty = tid >> 5;
        #pragma unroll
        for (int j = 0; j < 4; ++j)
            tl[ty + j * 8][tx] = src[(size_t)(k0 + ty + j * 8) * N + n0 + tx];
        __syncthreads();
        #pragma unroll
        for (int j = 0; j < 4; ++j)
            dst[(size_t)(n0 + ty + j * 8) * K + k0 + tx] = f2bf(tl[tx][ty + j * 8]);
        return;
    }
    if (bid < PREP_CB_END) {                   // ---- bias concat ----
        int i = (bid - PREP_W2_END) * 256 + tid;
        if (i < 2304)
            bqkv[i] = i < 768 ? bq[i] : (i < 1536 ? bk[i - 768] : bv[i - 1536]);
        return;
    }
    // ---- routing (single block) ----
    if (tid < 4) cnt[tid] = 0;
    __syncthreads();
    for (int t = tid; t < MB_TOK; t += 256) atomicAdd(&cnt[wl[t] & 3], 1);
    __syncthreads();
    if (tid == 0) {
        off[0] = 0;
        for (int e = 0; e < 4; ++e) off[e + 1] = off[e] + cnt[e];
        int idx = 0;
        for (int e = 0; e < 4; ++e)
            for (int s = 0; s < cnt[e]; s += 128)
                fmap[idx++] = make_int4(e, off[e], s, cnt[e] - s);
        for (; idx < 72; ++idx) fmap[idx] = make_int4(-1, 0, 0, 0);
        int idx2 = 0;
        for (int e = 0; e < 4; ++e)
            for (int s = 0; s < cnt[e]; s += 64)
                fmap64[idx2++] = make_int4(e, off[e], s, cnt[e] - s);
        for (; idx2 < 144; ++idx2) fmap64[idx2] = make_int4(-1, 0, 0, 0);
        for (int e = 0; e < 5; ++e) eoff[e] = off[e];
        for (int e = 0; e < 4; ++e) cur[e] = off[e];
    }
    __syncthreads();
    for (int t = tid; t < MB_TOK; t += 256) {
        int e = wl[t] & 3;
        int pos = atomicAdd(&cur[e], 1);
        perm[pos] = t;
    }
}

// ---------- V transpose: qkv bf16 V-cols -> vT[bh][d][key] ----------
__global__ __launch_bounds__(256) void vT_kernel(
    const u16* __restrict__ qkv, u16* __restrict__ vT)
{
    __shared__ u16 tl[32][33];
    int bh = blockIdx.z;
    int b = bh / HH, h = bh % HH;
    int key0 = blockIdx.x * 32;
    int d0 = blockIdx.y * 32;
    int tx = threadIdx.x & 31, ty = threadIdx.x >> 5;
    const u16* src = qkv + ((size_t)b * SEQ + key0) * 2304 + 1536 + h * 64 + d0;
    #pragma unroll
    for (int j = 0; j < 4; ++j)
        tl[ty + j * 8][tx] = src[(size_t)(ty + j * 8) * 2304 + tx];
    __syncthreads();
    u16* dst = vT + ((size_t)bh * 64 + d0) * SEQ + key0;
    #pragma unroll
    for (int j = 0; j < 4; ++j)
        dst[(size_t)(ty + j * 8) * SEQ + tx] = tl[tx][ty + j * 8];
}

// ---------- GEMM: C[M,N] = A[M,K](bf16) * Bt[N,K](bf16)^T + bias ----------
// MODE 0: dense. MODE 1: A rows via perm (FFN1). MODE 2: C rows via perm (FFN2).
// TM: M-tile (128 or 64). N-tile 128. BK=32. 2-buffer, stage-after-barrier.
// GCH=0: bt-major order (tn fastest) — for small B (fits L2 across sweeps).
// GCH>0: chunked tn-major — per XCD, GCH bt-blocks run consecutively per tn,
//        so each B panel is fetched once and reused GCH times, and the
//        chunk's A panels stay L2-resident across all tn sweeps. Requires
//        bpx % GCH == 0.
template<int MODE, int TM, int GCH, bool RELU, bool RES, bool ST32, bool ST16>
__global__ __launch_bounds__(256, (TM == 64) ? 6 : 4) void gemm_bt_kernel(
    const u16* __restrict__ A, const u16* __restrict__ Bt,
    const float* __restrict__ bias, const float* __restrict__ res,
    float* __restrict__ out32, u16* __restrict__ out16,
    int nbt, int N, int K, int ntn,
    const int* __restrict__ perm, const int4* __restrict__ fmap)
{
    constexpr int ALD = TM * 32;
    constexpr int NN  = (TM == 64) ? 2 : 4;    // n-frags per wave
    __shared__ __attribute__((aligned(16))) u16 As[2][ALD];
    __shared__ __attribute__((aligned(16))) u16 Bs[2][4096];
    int tid = threadIdx.x;
    int wv = tid >> 6, ln = tid & 63;
    int bpx = gridDim.x / (ntn << 3);
    int jj = blockIdx.x >> 3;
    int bt, tn;
    if (GCH > 0) {
        int pc = GCH * ntn;
        int chunk = jj / pc, rem = jj % pc;
        bt = (blockIdx.x & 7) * bpx + chunk * GCH + rem % GCH;
        tn = (rem / GCH) * 128;
    } else {
        bt = (blockIdx.x & 7) * bpx + jj / ntn;
        tn = (jj % ntn) * 128;
    }
    if (bt >= nbt) return;

    int seg = 0, ms = 0, mb = TM, tm = 0;
    if (MODE != 0) {
        int4 ent = fmap[bt];
        if (ent.x < 0) return;
        seg = ent.y; ms = ent.z; mb = ent.w; if (mb > TM) mb = TM;
        Bt += (size_t)ent.x * N * K;
        bias += ent.x * N;
    } else {
        tm = bt * TM;
    }

    f32x4 acc[4][NN];
    #pragma unroll
    for (int i = 0; i < 4; ++i)
        #pragma unroll
        for (int j = 0; j < NN; ++j) acc[i][j] = f32x4{0.f, 0.f, 0.f, 0.f};

    int wr = (TM == 128) ? (wv >> 1) : 0;
    int wcol0 = (TM == 128) ? (wv & 1) * 64 : wv * 32;
    int lr = ln & 15, hi = ln >> 4;
    int nk = K / 32;

    // per-thread staging source bases (row const across K-steps)
    const u16* asrc[2];
    const u16* bsrc[2];
    #pragma unroll
    for (int i = 0; i < 2; ++i) {
        int rA = (TM == 128) ? ((wv * 2 + i) * 16 + (ln >> 2))
                             : (wv * 16 + (ln >> 2));
        if (TM == 128 || i == 0) {
            int am = rA < mb ? rA : (mb - 1);
            size_t arow;
            if (MODE == 1)      arow = (size_t)perm[seg + ms + am];
            else if (MODE == 2) arow = (size_t)(seg + ms + am);
            else                arow = (size_t)(tm + rA);
            asrc[i] = A + arow * K + (ln & 3) * 8;
        }
        int rB = (wv * 2 + i) * 16 + (ln >> 2);
        bsrc[i] = Bt + (size_t)(tn + rB) * K + (ln & 3) * 8;
    }
    int aofs0 = (TM == 128) ? (wv * 2) * 512 : wv * 512;

#define GSTAGE(bf_, k0_) do {                                             \
    gload_lds16(asrc[0] + (k0_), &As[bf_][aofs0]);                        \
    if (TM == 128) gload_lds16(asrc[1] + (k0_), &As[bf_][aofs0 + 512]);   \
    gload_lds16(bsrc[0] + (k0_), &Bs[bf_][(wv * 2) * 512]);               \
    gload_lds16(bsrc[1] + (k0_), &Bs[bf_][(wv * 2 + 1) * 512]);           \
} while (0)

    GSTAGE(0, 0);
    for (int kk = 0; kk < nk; ++kk) {
        int bf = kk & 1;
        __syncthreads();                       // buf[bf] ready (vmcnt drained)
        if (kk + 1 < nk) GSTAGE(bf ^ 1, (kk + 1) * 32);
        bf16x8 a[4], b[NN];
        #pragma unroll
        for (int m = 0; m < 4; ++m)
            a[m] = *(const bf16x8*)&As[bf][(wr * 64 + m * 16 + lr) * 32 + hi * 8];
        #pragma unroll
        for (int n = 0; n < NN; ++n)
            b[n] = *(const bf16x8*)&Bs[bf][(wcol0 + n * 16 + lr) * 32 + hi * 8];
        #pragma unroll
        for (int m = 0; m < 4; ++m)
            #pragma unroll
            for (int n = 0; n < NN; ++n)
                acc[m][n] = mfma16(a[m], b[n], acc[m][n]);
    }
#undef GSTAGE

    // epilogue: C/D layout col=lane&15, row=(lane>>4)*4+i
    #pragma unroll
    for (int m = 0; m < 4; ++m) {
        int rb = wr * 64 + m * 16 + hi * 4;
        #pragma unroll
        for (int n = 0; n < NN; ++n) {
            int gcol = tn + wcol0 + n * 16 + lr;
            float bvv = bias[gcol];
            #pragma unroll
            for (int i = 0; i < 4; ++i) {
                int rml = rb + i;
                float v = acc[m][n][i] + bvv;
                if (RELU) v = v > 0.f ? v : 0.f;
                if (MODE == 0) {
                    size_t grow = (size_t)(tm + rml);
                    if (RES) v += res[grow * N + gcol];
                    if (ST32) out32[grow * N + gcol] = v;
                    if (ST16) out16[grow * N + gcol] = f2bf(v);
                } else {
                    if (rml < mb) {
                        size_t orow = (MODE == 1) ? (size_t)(seg + ms + rml)
                                                  : (size_t)perm[seg + ms + rml];
                        if (ST32) out32[orow * N + gcol] = v;
                        if (ST16) out16[orow * N + gcol] = f2bf(v);
                    }
                }
            }
        }
    }
}

// ---------- flash attention: 32x32 MFMA, 32 q/wave, double-buffered K/V ----------
__global__ __launch_bounds__(256, 4) void attn_kernel(
    const u16* __restrict__ qkv, const u16* __restrict__ vT,
    u16* __restrict__ ctx)
{
    __shared__ __attribute__((aligned(16))) u16 Ks[2][4096];
    __shared__ __attribute__((aligned(16))) u16 Vs[2][4096];
    int tid = threadIdx.x;
    int wv = tid >> 6, ln = tid & 63;
    int qv = ln & 31, hi = ln >> 5;
    int bid = blockIdx.x;
    int bh = (bid & 7) * 6 + ((bid >> 3) % 6);
    int qt = (bid >> 3) / 6;
    int b = bh / HH, h = bh % HH;
    int q0 = qt * 128 + wv * 32;
    size_t qrowb = (size_t)(b * SEQ + q0);
    const float C = 0.125f * LOG2E;

    bf16x8 qf[4];
    {
        const u16* qp = qkv + (qrowb + qv) * 2304 + h * 64 + hi * 8;
        #pragma unroll
        for (int ds = 0; ds < 4; ++ds) qf[ds] = *(const bf16x8*)(qp + ds * 16);
    }

    int csrc = 8 * ((ln & 7) ^ (ln >> 3));
    const size_t kbase = (size_t)b * SEQ * 2304 + 768 + h * 64;
    const u16* vtb = vT + (size_t)bh * 64 * SEQ;
    const u16* kp0 = qkv + kbase + (size_t)(wv * 16 + (ln >> 3)) * 2304 + csrc;
    const u16* kp1 = kp0 + (size_t)8 * 2304;
    const u16* vp0 = vtb + (size_t)(wv * 16 + (ln >> 3)) * SEQ + csrc;
    const u16* vp1 = vp0 + (size_t)8 * SEQ;

#define ATTN_STAGE(bf_, t_) do {                                          \
    gload_lds16(kp0 + (size_t)(t_) * 64 * 2304, &Ks[bf_][(wv * 2) * 512]);\
    gload_lds16(kp1 + (size_t)(t_) * 64 * 2304, &Ks[bf_][(wv * 2 + 1) * 512]);\
    gload_lds16(vp0 + (size_t)(t_) * 64, &Vs[bf_][(wv * 2) * 512]);       \
    gload_lds16(vp1 + (size_t)(t_) * 64, &Vs[bf_][(wv * 2 + 1) * 512]);   \
} while (0)

    f32x16 oacc[2];
    #pragma unroll
    for (int i = 0; i < 2; ++i)
        #pragma unroll
        for (int r = 0; r < 16; ++r) oacc[i][r] = 0.f;
    float m_run = -INFINITY, l_run = 0.f;
    int ksw = (qv & 7) * 8;

    ATTN_STAGE(0, 0);

    for (int kt = 0; kt < SEQ / 64; ++kt) {
        int bf = kt & 1;
        __syncthreads();
        if (kt + 1 < SEQ / 64) ATTN_STAGE(bf ^ 1, kt + 1);

        f32x16 s0, s1;
        #pragma unroll
        for (int r = 0; r < 16; ++r) { s0[r] = 0.f; s1[r] = 0.f; }
        #pragma unroll
        for (int ds = 0; ds < 4; ++ds) {
            bf16x8 ka0 = *(const bf16x8*)&Ks[bf][qv * 64 + ((ds * 16 + hi * 8) ^ ksw)];
            bf16x8 ka1 = *(const bf16x8*)&Ks[bf][(32 + qv) * 64 + ((ds * 16 + hi * 8) ^ ksw)];
            s0 = mfma32(ka0, qf[ds], s0);
            s1 = mfma32(ka1, qf[ds], s1);
        }

        float tmax = s0[0];
        #pragma unroll
        for (int r = 1; r < 16; ++r) tmax = fmaxf(tmax, s0[r]);
        #pragma unroll
        for (int r = 0; r < 16; ++r) tmax = fmaxf(tmax, s1[r]);
        tmax = fmaxf(tmax, __shfl_xor(tmax, 32));

        if (!__all(tmax - m_run <= 64.f)) {   // defer-max (T13), 8 nats
            float m_new = fmaxf(m_run, tmax);
            float corr = exp2_hw((m_run - m_new) * C);
            l_run *= corr;
            #pragma unroll
            for (int i = 0; i < 2; ++i)
                #pragma unroll
                for (int r = 0; r < 16; ++r) oacc[i][r] *= corr;
            m_run = m_new;
        }
        float c2 = -m_run * C;
        float psum = 0.f;
        #pragma unroll
        for (int r = 0; r < 16; ++r) {
            s0[r] = exp2_hw(fmaf(s0[r], C, c2)); psum += s0[r];
            s1[r] = exp2_hw(fmaf(s1[r], C, c2)); psum += s1[r];
        }
        l_run += psum;

        #pragma unroll
        for (int kb = 0; kb < 2; ++kb) {
            #pragma unroll
            for (int hc = 0; hc < 2; ++hc) {
                const f32x16& sv = kb ? s1 : s0;
                unsigned x0 = cvt_pk_bf16(sv[8 * hc + 0], sv[8 * hc + 1]);
                unsigned x1 = cvt_pk_bf16(sv[8 * hc + 2], sv[8 * hc + 3]);
                unsigned x2 = cvt_pk_bf16(sv[8 * hc + 4], sv[8 * hc + 5]);
                unsigned x3 = cvt_pk_bf16(sv[8 * hc + 6], sv[8 * hc + 7]);
                unsigned t0 = hi ? x0 : x2, t1 = hi ? x1 : x3;
                unsigned r0 = (unsigned)__shfl_xor((int)t0, 32);
                unsigned r1 = (unsigned)__shfl_xor((int)t1, 32);
                union { bf16x8 v; unsigned u[4]; } pf;
                pf.u[0] = hi ? r0 : x0; pf.u[1] = hi ? r1 : x1;
                pf.u[2] = hi ? x2 : r0; pf.u[3] = hi ? x3 : r1;
                int kc = (kb * 32 + hc * 16 + hi * 8) ^ ksw;
                #pragma unroll
                for (int dblk = 0; dblk < 2; ++dblk) {
                    bf16x8 va = *(const bf16x8*)&Vs[bf][(dblk * 32 + qv) * 64 + kc];
                    oacc[dblk] = mfma32(va, pf.v, oacc[dblk]);
                }
            }
        }
    }
#undef ATTN_STAGE

    float l_tot = l_run + __shfl_xor(l_run, 32);
    float inv = 1.f / l_tot;

    __syncthreads();
    u16* eb = &Ks[0][0] + wv * 2048;
    #pragma unroll
    for (int dblk = 0; dblk < 2; ++dblk)
        #pragma unroll
        for (int r = 0; r < 16; r += 2) {
            int d = dblk * 32 + (r & 3) + 8 * (r >> 2) + 4 * hi;
            unsigned pk = cvt_pk_bf16(oacc[dblk][r] * inv, oacc[dblk][r + 1] * inv);
            *(unsigned*)&eb[qv * 64 + (d ^ ((qv & 7) * 8))] = pk;
        }
    __syncthreads();
    {
        u16* ctr = ctx + (qrowb + qv) * DM + h * 64 + hi * 32;
        #pragma unroll
        for (int g = 0; g < 4; ++g) {
            bf16x8 vv = *(const bf16x8*)&eb[qv * 64 + ((hi * 32 + g * 8) ^ ((qv & 7) * 8))];
            *(bf16x8*)(ctr + g * 8) = vv;
        }
    }
}

// ---------- way classifier: logits = outb(bf16) @ wcls + bcls ----------
__global__ __launch_bounds__(256) void cls_kernel(
    const u16* __restrict__ outm, const float* __restrict__ wcls,
    const float* __restrict__ bcls, float* __restrict__ dst)
{
    int row = blockIdx.x, t = threadIdx.x;
    const u16* xr = outm + (size_t)row * DM;
    float a0 = 0, a1 = 0, a2 = 0, a3 = 0;
    for (int j = t; j < DM; j += 256) {
        float xv = bf2f(xr[j]);
        float4 wv4 = *(const float4*)(const void*)(wcls + (size_t)j * 4);
        a0 += xv * wv4.x; a1 += xv * wv4.y; a2 += xv * wv4.z; a3 += xv * wv4.w;
    }
    #pragma unroll
    for (int k = 1; k < 64; k <<= 1) {
        a0 += __shfl_xor(a0, k); a1 += __shfl_xor(a1, k);
        a2 += __shfl_xor(a2, k); a3 += __shfl_xor(a3, k);
    }
    __shared__ float red[4][4];
    if ((t & 63) == 0) {
        int wid = t >> 6;
        red[wid][0] = a0; red[wid][1] = a1; red[wid][2] = a2; red[wid][3] = a3;
    }
    __syncthreads();
    if (t < 4)
        dst[(size_t)row * 4 + t] =
            red[0][t] + red[1][t] + red[2][t] + red[3][t] + bcls[t];
}

// ---------- launch ----------
extern "C" void kernel_launch(void* const* d_in, const int* in_sizes, int n_in,
                              void* d_out, int out_size, void* d_ws, size_t ws_size,
                              hipStream_t stream) {
    const float* x      = (const float*)d_in[0];
    const int*   wl     = (const int*)d_in[1];        // int inputs are int32
    const float* ln_g   = (const float*)d_in[2];
    const float* ln_b   = (const float*)d_in[3];
    const float* wq     = (const float*)d_in[4];
    const float* bq     = (const float*)d_in[5];
    const float* wk     = (const float*)d_in[6];
    const float* bk     = (const float*)d_in[7];
    const float* wvv    = (const float*)d_in[8];
    const float* bv     = (const float*)d_in[9];
    const float* wo     = (const float*)d_in[10];
    const float* bo     = (const float*)d_in[11];
    const float* wcls   = (const float*)d_in[12];
    const float* bcls   = (const float*)d_in[13];
    const float* w1     = (const float*)d_in[14];
    const float* b1     = (const float*)d_in[15];
    const float* w2     = (const float*)d_in[16];
    const float* b2     = (const float*)d_in[17];
    float* out = (float*)d_out;

    char* ws = (char*)d_ws;
    u16*   xn    = (u16*)  (ws + 0);            // 12,582,912 B
    u16*   qkv   = (u16*)  (ws + 12582912);     // 37,748,736 B
    u16*   hbuf  = (u16*)  (ws + 0);            // reuse xn+qkv (50,331,648 B)
    u16*   ctx   = (u16*)  (ws + 50331648);     // 12,582,912
    u16*   outb  = (u16*)  (ws + 62914560);     // 12,582,912
    u16*   wqkvt = (u16*)  (ws + 75497472);     // 3,538,944
    u16*   wot   = (u16*)  (ws + 79036416);     // 1,179,648
    u16*   w1t   = (u16*)  (ws + 80216064);     // 18,874,368
    u16*   w2t   = (u16*)  (ws + 99090432);     // 18,874,368
    float* bqkv  = (float*)(ws + 117964800);    // 9,216
    int*   perm  = (int*)  (ws + 117974016);    // 32,768
    int*   eoff  = (int*)  (ws + 118006784);    // 32
    int4*  fmap  = (int4*) (ws + 118006816);    // 1,152 (72 entries)
    int4*  fmap64= (int4*) (ws + 118007968);    // 2,304 (144 entries)
    u16*   vT    = (u16*)  (ws + 118010272);    // 12,582,912 (16B aligned)

    // fused prep: LN + weight transposes + bias concat + routing
    prep_kernel<<<PREP_GRID, 256, 0, stream>>>(
        x, ln_g, ln_b, xn, wq, wk, wvv, wo, wqkvt, wot,
        w1, w1t, w2, w2t, bq, bk, bv, bqkv, wl, perm, eoff, fmap, fmap64);

    // QKV: TM=128, bt-major (B 3.5MB stays L2-resident), grid = 8*8*18
    gemm_bt_kernel<0, 128, 0, false, false, false, true><<<1152, 256, 0, stream>>>(
        xn, wqkvt, bqkv, nullptr, nullptr, qkv, 64, 2304, 768, 18, nullptr, nullptr);

    // V transpose for attention PV operand
    vT_kernel<<<dim3(64, 2, 48), 256, 0, stream>>>(qkv, vT);

    attn_kernel<<<768, 256, 0, stream>>>(qkv, vT, ctx);

    // WO + residual -> outb (bf16)   TM=64, bt-major (B 1.2MB resident), 8*16*6
    gemm_bt_kernel<0, 64, 0, false, true, false, true><<<768, 256, 0, stream>>>(
        ctx, wot, bo, x, nullptr, outb, 128, 768, 768, 6, nullptr, nullptr);

    cls_kernel<<<MB_TOK, 256, 0, stream>>>(outb, wcls, bcls, out + (size_t)MB_TOK * DM);

    // FFN1: TM=128, GCH=9 tn-major per XCD (A 1.8MB resident, B panels
    // fetched once each), grid = 8*9*24
    gemm_bt_kernel<1, 128, 9, true, false, false, true><<<1728, 256, 0, stream>>>(
        outb, w1t, b1, nullptr, nullptr, hbuf, 72, DFF, 768, 24, perm, fmap);

    // FFN2: TM=64, GCH=6 chunked tn-major, grid = 8*18*6 (bpx=18, pad bt)
    gemm_bt_kernel<2, 64, 6, false, false, true, false><<<864, 256, 0, stream>>>(
        hbuf, w2t, b2, nullptr, out, nullptr, 144, 768, DFF, 6, perm, fmap64);
}